// Round 11
// baseline (100.115 us; speedup 1.0000x reference)
//
#include <hip/hip_runtime.h>

// Problem constants (B=1 throughout)
constexpr int kH  = 1024;
constexpr int kS  = 48;
constexpr int kNH = 32;
constexpr int kDH = 32;
constexpr float kSF = 0.2f;
// Output: [48, 48*32*32*32] f32. Row x = O[x] (32x32 = 1024 f32) tiled 1536 times.
constexpr int kRepsPerRow = kS * kNH;          // 1536
constexpr int kRowF4      = kRepsPerRow * 256; // 393216 float4 per output row

constexpr int kKC = 8;                                       // k-chunks in split-K proj
constexpr size_t kPartialFloats = (size_t)kKC * 3 * kS * kH; // 4.5 MiB of f32
constexpr size_t kNeedFloats    = kPartialFloats + (size_t)kS * kH; // + O buffer

typedef float f32x4 __attribute__((ext_vector_type(4)));

__device__ __forceinline__ f32x4 ld4v(const float* p) {
    return *reinterpret_cast<const f32x4*>(p);
}
__device__ __forceinline__ float dot4v(f32x4 a, f32x4 b) {
    return a.x * b.x + a.y * b.y + a.z * b.z + a.w * b.w;
}
__device__ __forceinline__ float4 ld4(const float* p) {
    return *reinterpret_cast<const float4*>(p);
}
__device__ __forceinline__ float dot4(float4 a, float4 b) {
    return a.x * b.x + a.y * b.y + a.z * b.z + a.w * b.w;
}

// ---------------------------------------------------------------------------
// Kernel 1: split-K register-tiled proj GEMM (unchanged from round 10).
// 192 blocks = 3 g x 8 o-tiles(128) x 8 k-chunks(128); 512 threads.
// Writes partial[kc][g][s][o]; reduced once by reduce_attn.
// ---------------------------------------------------------------------------
__global__ __launch_bounds__(512) void proj_split_kernel(
    const float* __restrict__ q, const float* __restrict__ k, const float* __restrict__ v,
    const float* __restrict__ Wq, const float* __restrict__ Wk, const float* __restrict__ Wv,
    float* __restrict__ partial)
{
    const int bid = blockIdx.x;        // 0..191
    const int g   = bid >> 6;          // 0..2
    const int rem = bid & 63;
    const int ot  = rem >> 3;          // 0..7
    const int kc  = rem & 7;           // 0..7
    const int o0  = ot * 128;
    const int k0  = kc * 128;
    const float* X = (g == 0) ? q : (g == 1) ? k : v;
    const float* W = (g == 0) ? Wq : (g == 1) ? Wk : Wv;

    __shared__ float Xs[kS][128];
    const int t = threadIdx.x;

#pragma unroll
    for (int r = 0; r < 3; ++r) {
        const int slot = r * 512 + t;
        const int s  = slot >> 5;
        const int kq = slot & 31;
        *reinterpret_cast<f32x4*>(&Xs[s][kq * 4]) = ld4v(X + s * kH + k0 + kq * 4);
    }
    __syncthreads();

    const int og    = t & 31;
    const int sbase = (t >> 5) * 3;    // 0,3,...,45

    float acc[3][4] = {};
    const float* w0p = W + (o0 + og      ) * kH + k0;
    const float* w1p = W + (o0 + og + 32 ) * kH + k0;
    const float* w2p = W + (o0 + og + 64 ) * kH + k0;
    const float* w3p = W + (o0 + og + 96 ) * kH + k0;

#pragma unroll 4
    for (int kq = 0; kq < 32; ++kq) {
        const f32x4 w0 = ld4v(w0p + kq * 4);
        const f32x4 w1 = ld4v(w1p + kq * 4);
        const f32x4 w2 = ld4v(w2p + kq * 4);
        const f32x4 w3 = ld4v(w3p + kq * 4);
#pragma unroll
        for (int i = 0; i < 3; ++i) {
            const f32x4 xv = *reinterpret_cast<const f32x4*>(&Xs[sbase + i][kq * 4]);
            acc[i][0] += dot4v(xv, w0);
            acc[i][1] += dot4v(xv, w1);
            acc[i][2] += dot4v(xv, w2);
            acc[i][3] += dot4v(xv, w3);
        }
    }

    float* P = partial + (size_t)(kc * 3 + g) * kS * kH;
#pragma unroll
    for (int i = 0; i < 3; ++i)
#pragma unroll
        for (int j = 0; j < 4; ++j)
            P[(sbase + i) * kH + o0 + og + j * 32] = acc[i][j];
}

// ---------------------------------------------------------------------------
// Kernel 2: reduce partials (ONCE) + attn core. 48 blocks x 256 threads.
// Block x: qrow/krow/vrow = bias + sum_kc partial rows (96 KB read, 4.5 MB
// chip-total), then the 32x32 attn core, then O[x] (4 KB) -> ws.
// ---------------------------------------------------------------------------
__global__ __launch_bounds__(256) void reduce_attn_kernel(
    const float* __restrict__ partial,
    const float* __restrict__ bq, const float* __restrict__ bk,
    const float* __restrict__ bv,
    float* __restrict__ O)
{
    const int x = blockIdx.x;
    const int t = threadIdx.x;

    __shared__ float qrow[kH];
    __shared__ float krow[kH];
    __shared__ float vrow[kH];
    __shared__ float sq[kNH];
    __shared__ float sk[kDH][kDH];    // sk[d][e]
    __shared__ float pT[kNH][kNH];    // pT[c][b] = p[b][c]

    {
        f32x4 aq = ld4v(bq + t * 4);
        f32x4 ak = ld4v(bk + t * 4);
        f32x4 av = ld4v(bv + t * 4);
#pragma unroll
        for (int kc = 0; kc < kKC; ++kc) {
            const float* base = partial + (size_t)(kc * 3) * kS * kH + (size_t)x * kH + t * 4;
            aq += ld4v(base);
            ak += ld4v(base + (size_t)kS * kH);
            av += ld4v(base + (size_t)2 * kS * kH);
        }
        *reinterpret_cast<f32x4*>(&qrow[t * 4]) = aq;
        *reinterpret_cast<f32x4*>(&krow[t * 4]) = ak;
        *reinterpret_cast<f32x4*>(&vrow[t * 4]) = av;
    }
    __syncthreads();

    if (t < kNH) {
        float a = 0.f;
#pragma unroll
        for (int d = 0; d < kDH; ++d) {
            float xq = qrow[t * kDH + d];
            a += xq * xq;
        }
        sq[t] = a * (1.0f / 1024.0f);
    }
    {
        const int d = t >> 3;
        const int eq = t & 7;
        float4 a = {0.f, 0.f, 0.f, 0.f};
#pragma unroll
        for (int n = 0; n < kNH; ++n) {
            const float kv = krow[n * kDH + d];
            const float4 qv = reinterpret_cast<const float4*>(qrow)[n * 8 + eq];
            a.x += kv * qv.x; a.y += kv * qv.y; a.z += kv * qv.z; a.w += kv * qv.w;
        }
        const float sc = 1.0f / 1024.0f;
        a.x *= sc; a.y *= sc; a.z *= sc; a.w *= sc;
        *reinterpret_cast<float4*>(&sk[d][eq * 4]) = a;
    }
    __syncthreads();

    {
        const int b = t >> 3;
        const int c0 = (t & 7) * 4;
        const float s0 = sq[b];
        float v0 = kSF * fabsf(sk[c0 + 0][b] - s0);
        float v1 = kSF * fabsf(sk[c0 + 1][b] - s0);
        float v2 = kSF * fabsf(sk[c0 + 2][b] - s0);
        float v3 = kSF * fabsf(sk[c0 + 3][b] - s0);
        float m = fmaxf(fmaxf(v0, v1), fmaxf(v2, v3));
        m = fmaxf(m, __shfl_xor(m, 1));
        m = fmaxf(m, __shfl_xor(m, 2));
        m = fmaxf(m, __shfl_xor(m, 4));
        float e0 = __expf(v0 - m);
        float e1 = __expf(v1 - m);
        float e2 = __expf(v2 - m);
        float e3 = __expf(v3 - m);
        float sum = e0 + e1 + e2 + e3;
        sum += __shfl_xor(sum, 1);
        sum += __shfl_xor(sum, 2);
        sum += __shfl_xor(sum, 4);
        const float inv = 1.0f / sum;
        pT[c0 + 0][b] = e0 * inv;
        pT[c0 + 1][b] = e1 * inv;
        pT[c0 + 2][b] = e2 * inv;
        pT[c0 + 3][b] = e3 * inv;
    }
    __syncthreads();

    {
        const int b = t >> 3;
        const int dq = t & 7;
        float4 acc = {0.f, 0.f, 0.f, 0.f};
#pragma unroll
        for (int c = 0; c < kNH; ++c) {
            const float pv = pT[c][b];
            const float4 vv = reinterpret_cast<const float4*>(vrow)[c * 8 + dq];
            acc.x += pv * vv.x; acc.y += pv * vv.y; acc.z += pv * vv.z; acc.w += pv * vv.w;
        }
        reinterpret_cast<float4*>(O + x * kH)[t] = acc;   // slot (b*8+dq) == t
    }
}

// ---------------------------------------------------------------------------
// Kernel 3: pure broadcast store machine. 4608 blocks = 48 rows x 96
// rep-groups of 16. No LDS, no syncthreads: each thread direct-loads its 4
// f32x4 of the (L2-hot, 4 KB) O row, then wave w writes reps rb*16+w*4..+3
// as one contiguous 16 KB span of NT stores.
// ---------------------------------------------------------------------------
__global__ __launch_bounds__(256) void bcast_kernel(
    const float* __restrict__ O, float* __restrict__ out)
{
    const int x  = blockIdx.x / 96;   // output row
    const int rb = blockIdx.x % 96;   // rep-group of 16
    const int w  = threadIdx.x >> 6;  // wave 0..3
    const int l  = threadIdx.x & 63;

    const f32x4* Orow = reinterpret_cast<const f32x4*>(O + x * kH);
    const f32x4 o0 = Orow[0 * 64 + l];
    const f32x4 o1 = Orow[1 * 64 + l];
    const f32x4 o2 = Orow[2 * 64 + l];
    const f32x4 o3 = Orow[3 * 64 + l];

    f32x4* base = reinterpret_cast<f32x4*>(out)
                + (size_t)x * kRowF4 + (size_t)(rb * 16 + w * 4) * 256 + l;
#pragma unroll
    for (int rep = 0; rep < 4; ++rep) {
        f32x4* p = base + rep * 256;
        __builtin_nontemporal_store(o0, p);
        __builtin_nontemporal_store(o1, p + 64);
        __builtin_nontemporal_store(o2, p + 128);
        __builtin_nontemporal_store(o3, p + 192);
    }
}

// ---------------------------------------------------------------------------
// Fallback path (round-7 verbatim) if ws is too small for the partials.
// ---------------------------------------------------------------------------
__global__ __launch_bounds__(256) void proj_kernel(
    const float* __restrict__ q, const float* __restrict__ k, const float* __restrict__ v,
    const float* __restrict__ Wq, const float* __restrict__ bq,
    const float* __restrict__ Wk, const float* __restrict__ bk,
    const float* __restrict__ Wv, const float* __restrict__ bv,
    float* __restrict__ ws)
{
    const int wid  = blockIdx.x * 4 + (threadIdx.x >> 6);
    const int lane = threadIdx.x & 63;
    const int g = wid >> 10;
    const int o = wid & 1023;

    const float *X, *W, *Bv;
    if (g == 0)      { X = q; W = Wq; Bv = bq; }
    else if (g == 1) { X = k; W = Wk; Bv = bk; }
    else             { X = v; W = Wv; Bv = bv; }
    float* OUT = ws + g * (kS * kH);

    const float* wr = W + o * kH + lane * 4;
    const float4 w0 = ld4(wr);
    const float4 w1 = ld4(wr + 256);
    const float4 w2 = ld4(wr + 512);
    const float4 w3 = ld4(wr + 768);

    float acc[kS];
#pragma unroll
    for (int s = 0; s < kS; ++s) {
        const float* xr = X + s * kH + lane * 4;
        acc[s] = dot4(ld4(xr), w0) + dot4(ld4(xr + 256), w1)
               + dot4(ld4(xr + 512), w2) + dot4(ld4(xr + 768), w3);
    }
#pragma unroll
    for (int s = 0; s < kS; ++s) {
        float a = acc[s];
        a += __shfl_xor(a, 1);
        a += __shfl_xor(a, 2);
        a += __shfl_xor(a, 4);
        a += __shfl_xor(a, 8);
        a += __shfl_xor(a, 16);
        a += __shfl_xor(a, 32);
        acc[s] = a;
    }
    if (lane == 0) {
        const float bo = Bv[o];
#pragma unroll
        for (int s = 0; s < kS; ++s) OUT[s * kH + o] = acc[s] + bo;
    }
}

__global__ __launch_bounds__(256) void fused_fallback_kernel(
    const float* __restrict__ ws, float* __restrict__ out)
{
    const int x  = blockIdx.x / 96;
    const int rb = blockIdx.x % 96;
    const int t  = threadIdx.x;

    __shared__ float qrow[kH];
    __shared__ float krow[kH];
    __shared__ float vrow[kH];
    __shared__ float sq[kNH];
    __shared__ float sk[kDH][kDH];
    __shared__ float pT[kNH][kNH];

    reinterpret_cast<float4*>(qrow)[t] = ld4(ws + x * kH + t * 4);
    reinterpret_cast<float4*>(krow)[t] = ld4(ws + (kS + x) * kH + t * 4);
    reinterpret_cast<float4*>(vrow)[t] = ld4(ws + (2 * kS + x) * kH + t * 4);
    __syncthreads();

    if (t < kNH) {
        float a = 0.f;
#pragma unroll
        for (int d = 0; d < kDH; ++d) { float xq = qrow[t * kDH + d]; a += xq * xq; }
        sq[t] = a * (1.0f / 1024.0f);
    }
    {
        const int d = t >> 3;
        const int eq = t & 7;
        float4 a = {0.f, 0.f, 0.f, 0.f};
#pragma unroll
        for (int n = 0; n < kNH; ++n) {
            const float kv = krow[n * kDH + d];
            const float4 qv = reinterpret_cast<const float4*>(qrow)[n * 8 + eq];
            a.x += kv * qv.x; a.y += kv * qv.y; a.z += kv * qv.z; a.w += kv * qv.w;
        }
        const float sc = 1.0f / 1024.0f;
        a.x *= sc; a.y *= sc; a.z *= sc; a.w *= sc;
        *reinterpret_cast<float4*>(&sk[d][eq * 4]) = a;
    }
    __syncthreads();
    {
        const int b = t >> 3;
        const int c0 = (t & 7) * 4;
        const float s0 = sq[b];
        float v0 = kSF * fabsf(sk[c0 + 0][b] - s0);
        float v1 = kSF * fabsf(sk[c0 + 1][b] - s0);
        float v2 = kSF * fabsf(sk[c0 + 2][b] - s0);
        float v3 = kSF * fabsf(sk[c0 + 3][b] - s0);
        float m = fmaxf(fmaxf(v0, v1), fmaxf(v2, v3));
        m = fmaxf(m, __shfl_xor(m, 1));
        m = fmaxf(m, __shfl_xor(m, 2));
        m = fmaxf(m, __shfl_xor(m, 4));
        float e0 = __expf(v0 - m);
        float e1 = __expf(v1 - m);
        float e2 = __expf(v2 - m);
        float e3 = __expf(v3 - m);
        float sum = e0 + e1 + e2 + e3;
        sum += __shfl_xor(sum, 1);
        sum += __shfl_xor(sum, 2);
        sum += __shfl_xor(sum, 4);
        const float inv = 1.0f / sum;
        pT[c0 + 0][b] = e0 * inv;
        pT[c0 + 1][b] = e1 * inv;
        pT[c0 + 2][b] = e2 * inv;
        pT[c0 + 3][b] = e3 * inv;
    }
    __syncthreads();
    {
        const int b = t >> 3;
        const int dq = t & 7;
        float4 acc = {0.f, 0.f, 0.f, 0.f};
#pragma unroll
        for (int c = 0; c < kNH; ++c) {
            const float pv = pT[c][b];
            const float4 vv = reinterpret_cast<const float4*>(vrow)[c * 8 + dq];
            acc.x += pv * vv.x; acc.y += pv * vv.y; acc.z += pv * vv.z; acc.w += pv * vv.w;
        }
        reinterpret_cast<float4*>(qrow)[t] = acc;
    }
    __syncthreads();
    {
        const int w = t >> 6;
        const int l = t & 63;
        const f32x4* OshF4 = reinterpret_cast<const f32x4*>(qrow);
        const f32x4 o0 = OshF4[0 * 64 + l];
        const f32x4 o1 = OshF4[1 * 64 + l];
        const f32x4 o2 = OshF4[2 * 64 + l];
        const f32x4 o3 = OshF4[3 * 64 + l];
        f32x4* base = reinterpret_cast<f32x4*>(out)
                    + (size_t)x * kRowF4 + (size_t)(rb * 16 + w * 4) * 256 + l;
#pragma unroll
        for (int rep = 0; rep < 4; ++rep) {
            f32x4* p = base + rep * 256;
            __builtin_nontemporal_store(o0, p);
            __builtin_nontemporal_store(o1, p + 64);
            __builtin_nontemporal_store(o2, p + 128);
            __builtin_nontemporal_store(o3, p + 192);
        }
    }
}

extern "C" void kernel_launch(void* const* d_in, const int* in_sizes, int n_in,
                              void* d_out, int out_size, void* d_ws, size_t ws_size,
                              hipStream_t stream)
{
    (void)in_sizes; (void)n_in; (void)out_size;
    const float* q  = (const float*)d_in[0];
    const float* k  = (const float*)d_in[1];
    const float* v  = (const float*)d_in[2];
    const float* Wq = (const float*)d_in[3];
    const float* bq = (const float*)d_in[4];
    const float* Wk = (const float*)d_in[5];
    const float* bk = (const float*)d_in[6];
    const float* Wv = (const float*)d_in[7];
    const float* bv = (const float*)d_in[8];

    float* ws  = (float*)d_ws;
    float* out = (float*)d_out;

    if (ws_size >= kNeedFloats * sizeof(float)) {
        float* O = ws + kPartialFloats;
        proj_split_kernel<<<192, 512, 0, stream>>>(q, k, v, Wq, Wk, Wv, ws);
        reduce_attn_kernel<<<kS, 256, 0, stream>>>(ws, bq, bk, bv, O);
        bcast_kernel<<<kS * 96, 256, 0, stream>>>(O, out);
    } else {
        proj_kernel<<<768, 256, 0, stream>>>(q, k, v, Wq, bq, Wk, bk, Wv, bv, ws);
        fused_fallback_kernel<<<kS * 96, 256, 0, stream>>>(ws, out);
    }
}

// Round 12
// 78.777 us; speedup vs baseline: 1.2709x; 1.2709x over previous
//
#include <hip/hip_runtime.h>

// Problem constants (B=1 throughout)
constexpr int kH  = 1024;
constexpr int kS  = 48;
constexpr int kNH = 32;
constexpr int kDH = 32;
constexpr float kSF = 0.2f;
// Output: [48, 48*32*32*32] f32. Row x = O[x] (32x32 = 1024 f32) tiled 1536 times.
constexpr int kRepsPerRow = kS * kNH;          // 1536
constexpr int kRowF4      = kRepsPerRow * 256; // 393216 float4 per output row

constexpr int kKC = 8;                                       // k-chunks in split-K proj
constexpr size_t kPartialFloats = (size_t)kKC * 3 * kS * kH; // 4.5 MiB of f32

typedef float f32x4 __attribute__((ext_vector_type(4)));

__device__ __forceinline__ f32x4 ld4v(const float* p) {
    return *reinterpret_cast<const f32x4*>(p);
}
__device__ __forceinline__ float dot4v(f32x4 a, f32x4 b) {
    return a.x * b.x + a.y * b.y + a.z * b.z + a.w * b.w;
}
__device__ __forceinline__ float4 ld4(const float* p) {
    return *reinterpret_cast<const float4*>(p);
}
__device__ __forceinline__ float dot4(float4 a, float4 b) {
    return a.x * b.x + a.y * b.y + a.z * b.z + a.w * b.w;
}

// ---------------------------------------------------------------------------
// proj_split_v2: split-K GEMM with LDS-staged, pad-swizzled W (the fix for
// the 4KB-lane-stride W scatter that made v1 L1-conflict-bound).
// 384 blocks = 3 g x 8 o-tiles(128) x 8 k-chunks(128) x 2 s-halves(24).
// 256 threads. Ws[128][129]: staged coalesced; +1 pad (129 = 1 mod 32) makes
// compute-reads hit bank og+4kq per lane -> conflict-free. Xs reads are
// half-wave broadcasts (free). Thread (og,sg) owns 3 s x 4 o; per kq:
// 4 Ws b128 + 3 Xs b128 -> 48 FMA. Writes partial[kc][g][s][o] (r10 layout).
// ---------------------------------------------------------------------------
__global__ __launch_bounds__(256) void proj_split_v2_kernel(
    const float* __restrict__ q, const float* __restrict__ k, const float* __restrict__ v,
    const float* __restrict__ Wq, const float* __restrict__ Wk, const float* __restrict__ Wv,
    float* __restrict__ partial)
{
    const int bid = blockIdx.x;        // 0..383
    const int g   = bid >> 7;          // 0..2
    const int rem = bid & 127;
    const int ot  = rem >> 4;          // 0..7
    const int kc  = (rem >> 1) & 7;    // 0..7
    const int sh  = rem & 1;           // 0..1
    const int o0  = ot * 128;
    const int k0  = kc * 128;
    const int s0  = sh * 24;
    const float* X = (g == 0) ? q : (g == 1) ? k : v;
    const float* W = (g == 0) ? Wq : (g == 1) ? Wk : Wv;

    __shared__ float Ws[128][129];     // 66,048 B; +1 pad for bank spread
    __shared__ float Xs[24][128];      // 12,288 B
    const int t = threadIdx.x;

    // Stage W tile: 128 rows x 32 f32x4, coalesced (consecutive t -> consecutive kq)
#pragma unroll
    for (int i = 0; i < 16; ++i) {
        const int slot = i * 256 + t;       // 0..4095
        const int row  = slot >> 5;         // 0..127
        const int kq   = slot & 31;         // 0..31
        const f32x4 wv = ld4v(W + (size_t)(o0 + row) * kH + k0 + kq * 4);
        Ws[row][kq * 4 + 0] = wv.x;
        Ws[row][kq * 4 + 1] = wv.y;
        Ws[row][kq * 4 + 2] = wv.z;
        Ws[row][kq * 4 + 3] = wv.w;
    }
    // Stage X half: 24 rows x 32 f32x4, coalesced
#pragma unroll
    for (int i = 0; i < 3; ++i) {
        const int slot = i * 256 + t;       // 0..767
        const int s  = slot >> 5;           // 0..23
        const int kq = slot & 31;
        *reinterpret_cast<f32x4*>(&Xs[s][kq * 4]) = ld4v(X + (size_t)(s0 + s) * kH + k0 + kq * 4);
    }
    __syncthreads();

    const int og    = t & 31;
    const int sbase = (t >> 5) * 3;    // 0,3,...,21 (local within s-half)

    float acc[3][4] = {};
#pragma unroll 4
    for (int kq = 0; kq < 32; ++kq) {
        const f32x4 w0 = *reinterpret_cast<const f32x4*>(&Ws[og      ][kq * 4]);
        const f32x4 w1 = *reinterpret_cast<const f32x4*>(&Ws[og + 32 ][kq * 4]);
        const f32x4 w2 = *reinterpret_cast<const f32x4*>(&Ws[og + 64 ][kq * 4]);
        const f32x4 w3 = *reinterpret_cast<const f32x4*>(&Ws[og + 96 ][kq * 4]);
#pragma unroll
        for (int i = 0; i < 3; ++i) {
            const f32x4 xv = *reinterpret_cast<const f32x4*>(&Xs[sbase + i][kq * 4]);
            acc[i][0] += dot4v(xv, w0);
            acc[i][1] += dot4v(xv, w1);
            acc[i][2] += dot4v(xv, w2);
            acc[i][3] += dot4v(xv, w3);
        }
    }

    float* P = partial + (size_t)(kc * 3 + g) * kS * kH;
#pragma unroll
    for (int i = 0; i < 3; ++i)
#pragma unroll
        for (int j = 0; j < 4; ++j)
            P[(size_t)(s0 + sbase + i) * kH + o0 + og + j * 32] = acc[i][j];
}

// ---------------------------------------------------------------------------
// OLD proj (round-2 variant) — fallback if ws too small.
// ---------------------------------------------------------------------------
__global__ __launch_bounds__(256) void proj_kernel(
    const float* __restrict__ q, const float* __restrict__ k, const float* __restrict__ v,
    const float* __restrict__ Wq, const float* __restrict__ bq,
    const float* __restrict__ Wk, const float* __restrict__ bk,
    const float* __restrict__ Wv, const float* __restrict__ bv,
    float* __restrict__ ws)
{
    const int wid  = blockIdx.x * 4 + (threadIdx.x >> 6);
    const int lane = threadIdx.x & 63;
    const int g = wid >> 10;
    const int o = wid & 1023;

    const float *X, *W, *Bv;
    if (g == 0)      { X = q; W = Wq; Bv = bq; }
    else if (g == 1) { X = k; W = Wk; Bv = bk; }
    else             { X = v; W = Wv; Bv = bv; }
    float* OUT = ws + g * (kS * kH);

    const float* wr = W + o * kH + lane * 4;
    const float4 w0 = ld4(wr);
    const float4 w1 = ld4(wr + 256);
    const float4 w2 = ld4(wr + 512);
    const float4 w3 = ld4(wr + 768);

    float acc[kS];
#pragma unroll
    for (int s = 0; s < kS; ++s) {
        const float* xr = X + s * kH + lane * 4;
        acc[s] = dot4(ld4(xr), w0) + dot4(ld4(xr + 256), w1)
               + dot4(ld4(xr + 512), w2) + dot4(ld4(xr + 768), w3);
    }
#pragma unroll
    for (int s = 0; s < kS; ++s) {
        float a = acc[s];
        a += __shfl_xor(a, 1);
        a += __shfl_xor(a, 2);
        a += __shfl_xor(a, 4);
        a += __shfl_xor(a, 8);
        a += __shfl_xor(a, 16);
        a += __shfl_xor(a, 32);
        acc[s] = a;
    }
    if (lane == 0) {
        const float bo = Bv[o];
#pragma unroll
        for (int s = 0; s < kS; ++s) OUT[s * kH + o] = acc[s] + bo;
    }
}

// ---------------------------------------------------------------------------
// Fused reduce + attn + broadcast (round-10 structure, measured-best node 2).
// 4608 blocks = 48 rows x 96 rep-groups of 16; contiguous-per-wave NT stores.
// ---------------------------------------------------------------------------
template <bool SPLIT>
__global__ __launch_bounds__(256) void fused_kernel(
    const float* __restrict__ src,
    const float* __restrict__ bq, const float* __restrict__ bk,
    const float* __restrict__ bv,
    float* __restrict__ out)
{
    const int x  = blockIdx.x / 96;   // output row 0..47
    const int rb = blockIdx.x % 96;   // rep-group of 16
    const int t  = threadIdx.x;

    __shared__ float qrow[kH];        // qp row, later reused as O
    __shared__ float krow[kH];
    __shared__ float vrow[kH];
    __shared__ float sq[kNH];
    __shared__ float sk[kDH][kDH];    // sk[d][e]
    __shared__ float pT[kNH][kNH];    // pT[c][b] = p[b][c]

    if constexpr (SPLIT) {
        f32x4 aq = ld4v(bq + t * 4);
        f32x4 ak = ld4v(bk + t * 4);
        f32x4 av = ld4v(bv + t * 4);
#pragma unroll
        for (int kc = 0; kc < kKC; ++kc) {
            const float* base = src + (size_t)(kc * 3) * kS * kH + (size_t)x * kH + t * 4;
            aq += ld4v(base);
            ak += ld4v(base + (size_t)kS * kH);
            av += ld4v(base + (size_t)2 * kS * kH);
        }
        *reinterpret_cast<f32x4*>(&qrow[t * 4]) = aq;
        *reinterpret_cast<f32x4*>(&krow[t * 4]) = ak;
        *reinterpret_cast<f32x4*>(&vrow[t * 4]) = av;
    } else {
        reinterpret_cast<float4*>(qrow)[t] = ld4(src + x * kH + t * 4);
        reinterpret_cast<float4*>(krow)[t] = ld4(src + (kS + x) * kH + t * 4);
        reinterpret_cast<float4*>(vrow)[t] = ld4(src + (2 * kS + x) * kH + t * 4);
    }
    __syncthreads();

    if (t < kNH) {
        float a = 0.f;
#pragma unroll
        for (int d = 0; d < kDH; ++d) {
            float xq = qrow[t * kDH + d];
            a += xq * xq;
        }
        sq[t] = a * (1.0f / 1024.0f);
    }
    {
        const int d = t >> 3;
        const int eq = t & 7;
        float4 a = {0.f, 0.f, 0.f, 0.f};
#pragma unroll
        for (int n = 0; n < kNH; ++n) {
            const float kv = krow[n * kDH + d];
            const float4 qv = reinterpret_cast<const float4*>(qrow)[n * 8 + eq];
            a.x += kv * qv.x; a.y += kv * qv.y; a.z += kv * qv.z; a.w += kv * qv.w;
        }
        const float sc = 1.0f / 1024.0f;
        a.x *= sc; a.y *= sc; a.z *= sc; a.w *= sc;
        *reinterpret_cast<float4*>(&sk[d][eq * 4]) = a;
    }
    __syncthreads();

    {
        const int b = t >> 3;
        const int c0 = (t & 7) * 4;
        const float s0 = sq[b];
        float v0 = kSF * fabsf(sk[c0 + 0][b] - s0);
        float v1 = kSF * fabsf(sk[c0 + 1][b] - s0);
        float v2 = kSF * fabsf(sk[c0 + 2][b] - s0);
        float v3 = kSF * fabsf(sk[c0 + 3][b] - s0);
        float m = fmaxf(fmaxf(v0, v1), fmaxf(v2, v3));
        m = fmaxf(m, __shfl_xor(m, 1));
        m = fmaxf(m, __shfl_xor(m, 2));
        m = fmaxf(m, __shfl_xor(m, 4));
        float e0 = __expf(v0 - m);
        float e1 = __expf(v1 - m);
        float e2 = __expf(v2 - m);
        float e3 = __expf(v3 - m);
        float sum = e0 + e1 + e2 + e3;
        sum += __shfl_xor(sum, 1);
        sum += __shfl_xor(sum, 2);
        sum += __shfl_xor(sum, 4);
        const float inv = 1.0f / sum;
        pT[c0 + 0][b] = e0 * inv;
        pT[c0 + 1][b] = e1 * inv;
        pT[c0 + 2][b] = e2 * inv;
        pT[c0 + 3][b] = e3 * inv;
    }
    __syncthreads();   // qrow no longer read past here -> reuse as O

    {
        const int b = t >> 3;
        const int dq = t & 7;
        float4 acc = {0.f, 0.f, 0.f, 0.f};
#pragma unroll
        for (int c = 0; c < kNH; ++c) {
            const float pv = pT[c][b];
            const float4 vv = reinterpret_cast<const float4*>(vrow)[c * 8 + dq];
            acc.x += pv * vv.x; acc.y += pv * vv.y; acc.z += pv * vv.z; acc.w += pv * vv.w;
        }
        reinterpret_cast<float4*>(qrow)[t] = acc;   // (b*8+dq) == t
    }
    __syncthreads();

    {
        const int w = t >> 6;
        const int l = t & 63;
        const f32x4* OshF4 = reinterpret_cast<const f32x4*>(qrow);
        const f32x4 o0 = OshF4[0 * 64 + l];
        const f32x4 o1 = OshF4[1 * 64 + l];
        const f32x4 o2 = OshF4[2 * 64 + l];
        const f32x4 o3 = OshF4[3 * 64 + l];

        f32x4* base = reinterpret_cast<f32x4*>(out)
                    + (size_t)x * kRowF4 + (size_t)(rb * 16 + w * 4) * 256 + l;
#pragma unroll
        for (int rep = 0; rep < 4; ++rep) {
            f32x4* p = base + rep * 256;
            __builtin_nontemporal_store(o0, p);
            __builtin_nontemporal_store(o1, p + 64);
            __builtin_nontemporal_store(o2, p + 128);
            __builtin_nontemporal_store(o3, p + 192);
        }
    }
}

extern "C" void kernel_launch(void* const* d_in, const int* in_sizes, int n_in,
                              void* d_out, int out_size, void* d_ws, size_t ws_size,
                              hipStream_t stream)
{
    (void)in_sizes; (void)n_in; (void)out_size;
    const float* q  = (const float*)d_in[0];
    const float* k  = (const float*)d_in[1];
    const float* v  = (const float*)d_in[2];
    const float* Wq = (const float*)d_in[3];
    const float* bq = (const float*)d_in[4];
    const float* Wk = (const float*)d_in[5];
    const float* bk = (const float*)d_in[6];
    const float* Wv = (const float*)d_in[7];
    const float* bv = (const float*)d_in[8];

    float* ws  = (float*)d_ws;
    float* out = (float*)d_out;

    if (ws_size >= kPartialFloats * sizeof(float)) {
        proj_split_v2_kernel<<<384, 256, 0, stream>>>(q, k, v, Wq, Wk, Wv, ws);
        fused_kernel<true><<<kS * 96, 256, 0, stream>>>(ws, bq, bk, bv, out);
    } else {
        proj_kernel<<<768, 256, 0, stream>>>(q, k, v, Wq, bq, Wk, bk, Wv, bv, ws);
        fused_kernel<false><<<kS * 96, 256, 0, stream>>>(ws, bq, bk, bv, out);
    }
}

// Round 13
// 77.386 us; speedup vs baseline: 1.2937x; 1.0180x over previous
//
#include <hip/hip_runtime.h>

// Problem constants (B=1 throughout)
constexpr int kH  = 1024;
constexpr int kS  = 48;
constexpr int kNH = 32;
constexpr int kDH = 32;
constexpr float kSF = 0.2f;
// Output: [48, 48*32*32*32] f32. Row x = O[x] (32x32 = 1024 f32) tiled 1536 times.
constexpr int kRepsPerRow = kS * kNH;          // 1536
constexpr int kRowF4      = kRepsPerRow * 256; // 393216 float4 per output row

constexpr int kKC = 8;                                       // k-chunks in split-K proj
constexpr size_t kPartialFloats = (size_t)kKC * 3 * kS * kH; // 4.5 MiB of f32

typedef float f32x4 __attribute__((ext_vector_type(4)));

__device__ __forceinline__ f32x4 ld4v(const float* p) {
    return *reinterpret_cast<const f32x4*>(p);
}
__device__ __forceinline__ float dot4v(f32x4 a, f32x4 b) {
    return a.x * b.x + a.y * b.y + a.z * b.z + a.w * b.w;
}
__device__ __forceinline__ float4 ld4(const float* p) {
    return *reinterpret_cast<const float4*>(p);
}
__device__ __forceinline__ float dot4(float4 a, float4 b) {
    return a.x * b.x + a.y * b.y + a.z * b.z + a.w * b.w;
}

// ---------------------------------------------------------------------------
// proj_split_v2b: identical to r12's v2 except the W pad is 132 (not 129).
// 132 keeps every row 16-BYTE ALIGNED (132*4 B = 528 = 33 f32x4) so the
// compute reads stay ds_read_b128 (129's odd-row 4B alignment forced a 4x
// scalar split). Row stride 33 f32x4 is odd -> b128 bank-group walk
// (og*33 + kq) mod 8 covers all 8 groups at 8 lanes/group per wave64 =
// the conflict-free floor for b128. Staging now uses vector LDS stores.
// 384 blocks = 3 g x 8 o-tiles(128) x 8 k-chunks(128) x 2 s-halves(24).
// ---------------------------------------------------------------------------
__global__ __launch_bounds__(256) void proj_split_v2_kernel(
    const float* __restrict__ q, const float* __restrict__ k, const float* __restrict__ v,
    const float* __restrict__ Wq, const float* __restrict__ Wk, const float* __restrict__ Wv,
    float* __restrict__ partial)
{
    const int bid = blockIdx.x;        // 0..383
    const int g   = bid >> 7;          // 0..2
    const int rem = bid & 127;
    const int ot  = rem >> 4;          // 0..7
    const int kc  = (rem >> 1) & 7;    // 0..7
    const int sh  = rem & 1;           // 0..1
    const int o0  = ot * 128;
    const int k0  = kc * 128;
    const int s0  = sh * 24;
    const float* X = (g == 0) ? q : (g == 1) ? k : v;
    const float* W = (g == 0) ? Wq : (g == 1) ? Wk : Wv;

    __shared__ float Ws[128][132];     // 67,584 B; pad=4 keeps 16B alignment
    __shared__ float Xs[24][128];      // 12,288 B
    const int t = threadIdx.x;

    // Stage W tile: 128 rows x 32 f32x4, coalesced global, vector LDS stores
#pragma unroll
    for (int i = 0; i < 16; ++i) {
        const int slot = i * 256 + t;       // 0..4095
        const int row  = slot >> 5;         // 0..127
        const int kq   = slot & 31;         // 0..31
        const f32x4 wv = ld4v(W + (size_t)(o0 + row) * kH + k0 + kq * 4);
        *reinterpret_cast<f32x4*>(&Ws[row][kq * 4]) = wv;
    }
    // Stage X half: 24 rows x 32 f32x4, coalesced
#pragma unroll
    for (int i = 0; i < 3; ++i) {
        const int slot = i * 256 + t;       // 0..767
        const int s  = slot >> 5;           // 0..23
        const int kq = slot & 31;
        *reinterpret_cast<f32x4*>(&Xs[s][kq * 4]) = ld4v(X + (size_t)(s0 + s) * kH + k0 + kq * 4);
    }
    __syncthreads();

    const int og    = t & 31;
    const int sbase = (t >> 5) * 3;    // 0,3,...,21 (local within s-half)

    float acc[3][4] = {};
#pragma unroll 4
    for (int kq = 0; kq < 32; ++kq) {
        const f32x4 w0 = *reinterpret_cast<const f32x4*>(&Ws[og      ][kq * 4]);
        const f32x4 w1 = *reinterpret_cast<const f32x4*>(&Ws[og + 32 ][kq * 4]);
        const f32x4 w2 = *reinterpret_cast<const f32x4*>(&Ws[og + 64 ][kq * 4]);
        const f32x4 w3 = *reinterpret_cast<const f32x4*>(&Ws[og + 96 ][kq * 4]);
#pragma unroll
        for (int i = 0; i < 3; ++i) {
            const f32x4 xv = *reinterpret_cast<const f32x4*>(&Xs[sbase + i][kq * 4]);
            acc[i][0] += dot4v(xv, w0);
            acc[i][1] += dot4v(xv, w1);
            acc[i][2] += dot4v(xv, w2);
            acc[i][3] += dot4v(xv, w3);
        }
    }

    float* P = partial + (size_t)(kc * 3 + g) * kS * kH;
#pragma unroll
    for (int i = 0; i < 3; ++i)
#pragma unroll
        for (int j = 0; j < 4; ++j)
            P[(size_t)(s0 + sbase + i) * kH + o0 + og + j * 32] = acc[i][j];
}

// ---------------------------------------------------------------------------
// OLD proj (round-2 variant) — fallback if ws too small.
// ---------------------------------------------------------------------------
__global__ __launch_bounds__(256) void proj_kernel(
    const float* __restrict__ q, const float* __restrict__ k, const float* __restrict__ v,
    const float* __restrict__ Wq, const float* __restrict__ bq,
    const float* __restrict__ Wk, const float* __restrict__ bk,
    const float* __restrict__ Wv, const float* __restrict__ bv,
    float* __restrict__ ws)
{
    const int wid  = blockIdx.x * 4 + (threadIdx.x >> 6);
    const int lane = threadIdx.x & 63;
    const int g = wid >> 10;
    const int o = wid & 1023;

    const float *X, *W, *Bv;
    if (g == 0)      { X = q; W = Wq; Bv = bq; }
    else if (g == 1) { X = k; W = Wk; Bv = bk; }
    else             { X = v; W = Wv; Bv = bv; }
    float* OUT = ws + g * (kS * kH);

    const float* wr = W + o * kH + lane * 4;
    const float4 w0 = ld4(wr);
    const float4 w1 = ld4(wr + 256);
    const float4 w2 = ld4(wr + 512);
    const float4 w3 = ld4(wr + 768);

    float acc[kS];
#pragma unroll
    for (int s = 0; s < kS; ++s) {
        const float* xr = X + s * kH + lane * 4;
        acc[s] = dot4(ld4(xr), w0) + dot4(ld4(xr + 256), w1)
               + dot4(ld4(xr + 512), w2) + dot4(ld4(xr + 768), w3);
    }
#pragma unroll
    for (int s = 0; s < kS; ++s) {
        float a = acc[s];
        a += __shfl_xor(a, 1);
        a += __shfl_xor(a, 2);
        a += __shfl_xor(a, 4);
        a += __shfl_xor(a, 8);
        a += __shfl_xor(a, 16);
        a += __shfl_xor(a, 32);
        acc[s] = a;
    }
    if (lane == 0) {
        const float bo = Bv[o];
#pragma unroll
        for (int s = 0; s < kS; ++s) OUT[s * kH + o] = acc[s] + bo;
    }
}

// ---------------------------------------------------------------------------
// Fused reduce + attn + broadcast (round-10/12 structure, unchanged).
// 4608 blocks = 48 rows x 96 rep-groups of 16; contiguous-per-wave NT stores.
// ---------------------------------------------------------------------------
template <bool SPLIT>
__global__ __launch_bounds__(256) void fused_kernel(
    const float* __restrict__ src,
    const float* __restrict__ bq, const float* __restrict__ bk,
    const float* __restrict__ bv,
    float* __restrict__ out)
{
    const int x  = blockIdx.x / 96;   // output row 0..47
    const int rb = blockIdx.x % 96;   // rep-group of 16
    const int t  = threadIdx.x;

    __shared__ float qrow[kH];        // qp row, later reused as O
    __shared__ float krow[kH];
    __shared__ float vrow[kH];
    __shared__ float sq[kNH];
    __shared__ float sk[kDH][kDH];    // sk[d][e]
    __shared__ float pT[kNH][kNH];    // pT[c][b] = p[b][c]

    if constexpr (SPLIT) {
        f32x4 aq = ld4v(bq + t * 4);
        f32x4 ak = ld4v(bk + t * 4);
        f32x4 av = ld4v(bv + t * 4);
#pragma unroll
        for (int kc = 0; kc < kKC; ++kc) {
            const float* base = src + (size_t)(kc * 3) * kS * kH + (size_t)x * kH + t * 4;
            aq += ld4v(base);
            ak += ld4v(base + (size_t)kS * kH);
            av += ld4v(base + (size_t)2 * kS * kH);
        }
        *reinterpret_cast<f32x4*>(&qrow[t * 4]) = aq;
        *reinterpret_cast<f32x4*>(&krow[t * 4]) = ak;
        *reinterpret_cast<f32x4*>(&vrow[t * 4]) = av;
    } else {
        reinterpret_cast<float4*>(qrow)[t] = ld4(src + x * kH + t * 4);
        reinterpret_cast<float4*>(krow)[t] = ld4(src + (kS + x) * kH + t * 4);
        reinterpret_cast<float4*>(vrow)[t] = ld4(src + (2 * kS + x) * kH + t * 4);
    }
    __syncthreads();

    if (t < kNH) {
        float a = 0.f;
#pragma unroll
        for (int d = 0; d < kDH; ++d) {
            float xq = qrow[t * kDH + d];
            a += xq * xq;
        }
        sq[t] = a * (1.0f / 1024.0f);
    }
    {
        const int d = t >> 3;
        const int eq = t & 7;
        float4 a = {0.f, 0.f, 0.f, 0.f};
#pragma unroll
        for (int n = 0; n < kNH; ++n) {
            const float kv = krow[n * kDH + d];
            const float4 qv = reinterpret_cast<const float4*>(qrow)[n * 8 + eq];
            a.x += kv * qv.x; a.y += kv * qv.y; a.z += kv * qv.z; a.w += kv * qv.w;
        }
        const float sc = 1.0f / 1024.0f;
        a.x *= sc; a.y *= sc; a.z *= sc; a.w *= sc;
        *reinterpret_cast<float4*>(&sk[d][eq * 4]) = a;
    }
    __syncthreads();

    {
        const int b = t >> 3;
        const int c0 = (t & 7) * 4;
        const float s0 = sq[b];
        float v0 = kSF * fabsf(sk[c0 + 0][b] - s0);
        float v1 = kSF * fabsf(sk[c0 + 1][b] - s0);
        float v2 = kSF * fabsf(sk[c0 + 2][b] - s0);
        float v3 = kSF * fabsf(sk[c0 + 3][b] - s0);
        float m = fmaxf(fmaxf(v0, v1), fmaxf(v2, v3));
        m = fmaxf(m, __shfl_xor(m, 1));
        m = fmaxf(m, __shfl_xor(m, 2));
        m = fmaxf(m, __shfl_xor(m, 4));
        float e0 = __expf(v0 - m);
        float e1 = __expf(v1 - m);
        float e2 = __expf(v2 - m);
        float e3 = __expf(v3 - m);
        float sum = e0 + e1 + e2 + e3;
        sum += __shfl_xor(sum, 1);
        sum += __shfl_xor(sum, 2);
        sum += __shfl_xor(sum, 4);
        const float inv = 1.0f / sum;
        pT[c0 + 0][b] = e0 * inv;
        pT[c0 + 1][b] = e1 * inv;
        pT[c0 + 2][b] = e2 * inv;
        pT[c0 + 3][b] = e3 * inv;
    }
    __syncthreads();   // qrow no longer read past here -> reuse as O

    {
        const int b = t >> 3;
        const int dq = t & 7;
        float4 acc = {0.f, 0.f, 0.f, 0.f};
#pragma unroll
        for (int c = 0; c < kNH; ++c) {
            const float pv = pT[c][b];
            const float4 vv = reinterpret_cast<const float4*>(vrow)[c * 8 + dq];
            acc.x += pv * vv.x; acc.y += pv * vv.y; acc.z += pv * vv.z; acc.w += pv * vv.w;
        }
        reinterpret_cast<float4*>(qrow)[t] = acc;   // (b*8+dq) == t
    }
    __syncthreads();

    {
        const int w = t >> 6;
        const int l = t & 63;
        const f32x4* OshF4 = reinterpret_cast<const f32x4*>(qrow);
        const f32x4 o0 = OshF4[0 * 64 + l];
        const f32x4 o1 = OshF4[1 * 64 + l];
        const f32x4 o2 = OshF4[2 * 64 + l];
        const f32x4 o3 = OshF4[3 * 64 + l];

        f32x4* base = reinterpret_cast<f32x4*>(out)
                    + (size_t)x * kRowF4 + (size_t)(rb * 16 + w * 4) * 256 + l;
#pragma unroll
        for (int rep = 0; rep < 4; ++rep) {
            f32x4* p = base + rep * 256;
            __builtin_nontemporal_store(o0, p);
            __builtin_nontemporal_store(o1, p + 64);
            __builtin_nontemporal_store(o2, p + 128);
            __builtin_nontemporal_store(o3, p + 192);
        }
    }
}

extern "C" void kernel_launch(void* const* d_in, const int* in_sizes, int n_in,
                              void* d_out, int out_size, void* d_ws, size_t ws_size,
                              hipStream_t stream)
{
    (void)in_sizes; (void)n_in; (void)out_size;
    const float* q  = (const float*)d_in[0];
    const float* k  = (const float*)d_in[1];
    const float* v  = (const float*)d_in[2];
    const float* Wq = (const float*)d_in[3];
    const float* bq = (const float*)d_in[4];
    const float* Wk = (const float*)d_in[5];
    const float* bk = (const float*)d_in[6];
    const float* Wv = (const float*)d_in[7];
    const float* bv = (const float*)d_in[8];

    float* ws  = (float*)d_ws;
    float* out = (float*)d_out;

    if (ws_size >= kPartialFloats * sizeof(float)) {
        proj_split_v2_kernel<<<384, 256, 0, stream>>>(q, k, v, Wq, Wk, Wv, ws);
        fused_kernel<true><<<kS * 96, 256, 0, stream>>>(ws, bq, bk, bv, out);
    } else {
        proj_kernel<<<768, 256, 0, stream>>>(q, k, v, Wq, bq, Wk, bk, Wv, bv, ws);
        fused_kernel<false><<<kS * 96, 256, 0, stream>>>(ws, bq, bk, bv, out);
    }
}